// Round 3
// baseline (110.407 us; speedup 1.0000x reference)
//
#include <hip/hip_runtime.h>

#define NBDT_BATCH 16384
#define NBDT_C 1024

// sigmoid(x) = 1/(1+exp(-x)); v_exp + v_rcp, ~1 ulp each.
__device__ __forceinline__ float fast_sigmoid(float x) {
    return __builtin_amdgcn_rcpf(1.0f + __expf(-x));
}

// One wave per row. Lane i owns leaves { k*256 + 4i + j : k=0..3, j=0..3 } so
// every global load/store is a perfectly coalesced lane-contiguous dwordx4.
//
// Register-lean restructure vs R2: leaf values are consumed immediately after
// load (blk-1/blk-2 sigmoids computed up front), and the blk-4..blk-128 level
// probabilities are folded into one running product pk[k] inside the butterfly.
// Live set shrinks from ~60 floats to ~20 -> <=64 VGPR -> 8 waves/SIMD for
// better memory-latency hiding.
__global__ __launch_bounds__(256, 8) void nbdt_kernel(const float* __restrict__ x,
                                                      float* __restrict__ y) {
    const int wave = (blockIdx.x * 256 + threadIdx.x) >> 6;
    const int lane = threadIdx.x & 63;
    const size_t rowbase = (size_t)wave * NBDT_C + (size_t)lane * 4;

    float4 v[4];
#pragma unroll
    for (int k = 0; k < 4; ++k)
        v[k] = *reinterpret_cast<const float4*>(x + rowbase + k * 256);

    float sigA[4], sigB[4], sig2[4], pk[4], s256[4];
#pragma unroll
    for (int k = 0; k < 4; ++k) {
        // blk=1 and blk=2 node probabilities (consume leaves now)
        sigA[k] = fast_sigmoid(v[k].x - v[k].y);
        sigB[k] = fast_sigmoid(v[k].z - v[k].w);
        const float s2a = v[k].x + v[k].y;
        const float s2b = v[k].z + v[k].w;
        sig2[k] = fast_sigmoid((s2a - s2b) * 0.5f);

        // butterfly up-sweep, folding blk=4..128 probs into running product
        float acc = s2a + s2b;  // s4
        float t, p;
        t = __shfl_xor(acc, 1);  p  = fast_sigmoid((acc - t) * (1.0f / 4.0f));   acc += t;
        t = __shfl_xor(acc, 2);  p *= fast_sigmoid((acc - t) * (1.0f / 8.0f));   acc += t;
        t = __shfl_xor(acc, 4);  p *= fast_sigmoid((acc - t) * (1.0f / 16.0f));  acc += t;
        t = __shfl_xor(acc, 8);  p *= fast_sigmoid((acc - t) * (1.0f / 32.0f));  acc += t;
        t = __shfl_xor(acc, 16); p *= fast_sigmoid((acc - t) * (1.0f / 64.0f));  acc += t;
        t = __shfl_xor(acc, 32); p *= fast_sigmoid((acc - t) * (1.0f / 128.0f)); acc += t;
        pk[k] = p;
        s256[k] = acc;
    }

    // top two levels (lane-uniform)
    const float pTop = fast_sigmoid((s256[0] + s256[1] - s256[2] - s256[3]) * (1.0f / 512.0f));
    const float qTop = 1.0f - pTop;
    const float p01  = fast_sigmoid((s256[0] - s256[1]) * (1.0f / 256.0f));
    const float p23  = fast_sigmoid((s256[2] - s256[3]) * (1.0f / 256.0f));
    float P[4];
    P[0] = pTop * p01;  P[1] = pTop - P[0];
    P[2] = qTop * p23;  P[3] = qTop - P[2];

#pragma unroll
    for (int k = 0; k < 4; ++k) {
        const float Pk = P[k] * pk[k];
        const float c0 = Pk * sig2[k];   // blk=2 left child
        const float c1 = Pk - c0;        // exact complement
        float4 o;
        o.x = c0 * sigA[k];
        o.y = c0 - o.x;
        o.z = c1 * sigB[k];
        o.w = c1 - o.z;
        *reinterpret_cast<float4*>(y + rowbase + k * 256) = o;
    }
}

extern "C" void kernel_launch(void* const* d_in, const int* in_sizes, int n_in,
                              void* d_out, int out_size, void* d_ws, size_t ws_size,
                              hipStream_t stream) {
    const float* x = (const float*)d_in[0];
    float* y = (float*)d_out;
    // 16384 rows, 1 row per wave, 4 waves per 256-thread block -> 4096 blocks.
    dim3 grid(NBDT_BATCH / 4);
    dim3 block(256);
    nbdt_kernel<<<grid, block, 0, stream>>>(x, y);
}